// Round 12
// baseline (211.106 us; speedup 1.0000x reference)
//
#include <hip/hip_runtime.h>

// ForwardSumLossWithBlank: CTC forward (alpha) loss, blank=0, targets=arange(text_len).
// B=32, T=2000 mel frames, C=400 classes. Output: scalar mean loss (fp32).
//
// Three-tier dispatch on ws_size:
//  F32 path (~131.4 MB): Pass A stores masked NORMALIZED probs as f32 [T][512],
//        permuted pairs (c,c+4) -> pass B's packed update reads ring float4s
//        directly (no bf16 converts, no staging regs). ~24 inst/step.
//  BF16 path (~66 MB): R10 kernel verbatim (proven: k_ctc 149 us, absmax 0.5).
//  SLOW path: R4 kernels (raw exp(logits), -lsum epilogue).
//
// R11 post-mortem: 2-wave state-split regressed (barrier+exchange ~120 cy/step,
// absmax 0.75) -> reverted. Single-wave cadence model (1 inst ~ 4 cy) validated
// across R6-R10: optimize by instruction count only.

static constexpr int B_ = 32;
static constexpr int T_ = 2000;
static constexpr int C_ = 400;
static constexpr float M0f    = 1e20f;
static constexpr float LOGM0f = 46.05170186f;   // ln(1e20) (fallback path)

typedef float f32x2 __attribute__((ext_vector_type(2)));

template <int CTRL>
__device__ __forceinline__ float dppmov(float v) {
    // mov_dpp, bound_ctrl=1: invalid-source lanes read 0 (safe: alphas >= 0).
    return __int_as_float(__builtin_amdgcn_update_dpp(
        0, __float_as_int(v), CTRL, 0xF, 0xF, true));
}

__device__ __forceinline__ float bcast0(float v) {
    return __int_as_float(__builtin_amdgcn_readfirstlane(__float_as_int(v)));
}

__device__ __forceinline__ unsigned bf16rne(float f) {
    unsigned u = __float_as_uint(f);
    u += 0x7FFFu + ((u >> 16) & 1u);
    return u >> 16;
}

// ---------------- Pass A: masked normalized probs ----------------
// mode f32  (pf32!=null): f32 probs, permuted pairs (c,c+4); ls[row] = p0
// mode bf16 (pbf!=null):  bf16 probs, permuted pairs (c,c+4); ls[row] = p0
// mode slow (both null):  ls[row] = ln(sum exp)
__global__ __launch_bounds__(256) void k_prob(const float* __restrict__ logits,
                                              const int* __restrict__ text_lens,
                                              float* __restrict__ pf32,
                                              unsigned short* __restrict__ pbf,
                                              float* __restrict__ ls) {
    const int lane = threadIdx.x & 63;
    const int row  = blockIdx.x * 4 + (threadIdx.x >> 6);   // grid = B*T/4 exactly
    const int b    = row / T_;
    const int tl   = text_lens[b];
    const float* __restrict__ r = logits + (size_t)row * C_;

    const int c0 = lane * 8;
    float v[8];
    if (c0 < C_) {           // row is 1600 B, 16B-aligned; lane<50 reads [c0, c0+8)
        const float4 a = *(const float4*)(r + c0);
        const float4 c = *(const float4*)(r + c0 + 4);
        v[0]=a.x; v[1]=a.y; v[2]=a.z; v[3]=a.w; v[4]=c.x; v[5]=c.y; v[6]=c.z; v[7]=c.w;
    } else {
#pragma unroll
        for (int e = 0; e < 8; ++e) v[e] = 0.f;             // masked below anyway
    }
    float ex[8]; float s = 0.f;
#pragma unroll
    for (int e = 0; e < 8; ++e) {
        const int c = c0 + e;
        const float t = (c < tl) ? __expf(v[e]) : 0.f;      // tl <= 400 -> cols>=400 masked
        ex[e] = t; s += t;
    }
#pragma unroll
    for (int off = 32; off; off >>= 1) s += __shfl_xor(s, off);

    if (pf32) {
        const float inv = 1.0f / s;
        // permuted: slot j = pairs (c0+j, c0+j+4); lane's 8 floats at row*512 + c0
        float4 s0, s1;
        s0.x = ex[0]*inv; s0.y = ex[4]*inv; s0.z = ex[1]*inv; s0.w = ex[5]*inv;
        s1.x = ex[2]*inv; s1.y = ex[6]*inv; s1.z = ex[3]*inv; s1.w = ex[7]*inv;
        float* dst = pf32 + (size_t)row * 512 + c0;
        *(float4*)dst = s0;
        *(float4*)(dst + 4) = s1;
        if (lane == 0) ls[row] = ex[0] * inv;               // p0 (col 0 always < tl)
    } else if (pbf) {
        const float inv = 1.0f / s;
        uint4 st;
        st.x = bf16rne(ex[0]*inv) | (bf16rne(ex[2]*inv) << 16);
        st.y = bf16rne(ex[1]*inv) | (bf16rne(ex[3]*inv) << 16);
        st.z = bf16rne(ex[4]*inv) | (bf16rne(ex[6]*inv) << 16);
        st.w = bf16rne(ex[5]*inv) | (bf16rne(ex[7]*inv) << 16);
        // NOTE: bf16 layout here must match k_ctc_bf16 (R10 layout): slot j of the
        // R10 kernel = pairs (c0+j, c0+j+4) with dword j = (col j, col j+4):
        uint4 st_r10;
        st_r10.x = bf16rne(ex[0]*inv) | (bf16rne(ex[4]*inv) << 16);
        st_r10.y = bf16rne(ex[1]*inv) | (bf16rne(ex[5]*inv) << 16);
        st_r10.z = bf16rne(ex[2]*inv) | (bf16rne(ex[6]*inv) << 16);
        st_r10.w = bf16rne(ex[3]*inv) | (bf16rne(ex[7]*inv) << 16);
        *(uint4*)(pbf + (size_t)row * 512 + c0) = st_r10;
        (void)st;
        if (lane == 0) ls[row] = ex[0] * inv;
    } else {
        if (lane == 0) ls[row] = __logf(s);
    }
}

// ---------------- Pass A2 (slow path only): per-sample sum of ln-denominators ----------------
__global__ __launch_bounds__(256) void k_lsum(const float* __restrict__ ls,
                                              const int* __restrict__ mel_lens,
                                              float* __restrict__ lsums) {
    const int b  = blockIdx.x;
    const int ml = mel_lens[b];
    float s = 0.f;
    for (int i = threadIdx.x; i < ml; i += 256) s += ls[(size_t)b * T_ + i];
#pragma unroll
    for (int off = 32; off; off >>= 1) s += __shfl_xor(s, off);
    __shared__ float ws[4];
    if ((threadIdx.x & 63) == 0) ws[threadIdx.x >> 6] = s;
    __syncthreads();
    if (threadIdx.x == 0) lsums[b] = (ws[0] + ws[1]) + (ws[2] + ws[3]);
}

// ---------------- shared packed pieces ----------------
// Slot j holds CTC pairs (lane*8+j, lane*8+4+j) as float2 (X=low, Y=high).
__device__ __forceinline__ void renorm_exp_pk(f32x2* __restrict__ Ae,
                                              f32x2* __restrict__ Ao, int& exacc) {
    const f32x2 m0 = __builtin_elementwise_max(__builtin_elementwise_max(Ae[0], Ao[0]),
                                               __builtin_elementwise_max(Ae[1], Ao[1]));
    const f32x2 m1 = __builtin_elementwise_max(__builtin_elementwise_max(Ae[2], Ao[2]),
                                               __builtin_elementwise_max(Ae[3], Ao[3]));
    const f32x2 m2 = __builtin_elementwise_max(m0, m1);
    float m = fmaxf(m2.x, m2.y);
    m = fmaxf(m, dppmov<0x111>(m));   // row_shr:1
    m = fmaxf(m, dppmov<0x112>(m));   // row_shr:2
    m = fmaxf(m, dppmov<0x114>(m));   // row_shr:4
    m = fmaxf(m, dppmov<0x118>(m));   // row_shr:8
    m = fmaxf(m, dppmov<0x142>(m));   // row_bcast:15
    m = fmaxf(m, dppmov<0x143>(m));   // row_bcast:31 -> lane 63 holds wave max
    const int wmb = __builtin_amdgcn_readlane(__float_as_int(m), 63);
    int ex = ((wmb >> 23) & 0xFF) - 127;
    if (ex < -60) ex = -60;                 // guard vs denorm/zero max
    exacc += ex - 66;
    const float scale = __int_as_float((unsigned)(193 - ex) << 23);  // 2^(66-ex), exact
    const f32x2 sc = {scale, scale};
#pragma unroll
    for (int j = 0; j < 4; ++j) { Ae[j] *= sc; Ao[j] *= sc; }
}

__device__ __forceinline__ void update_pk(const float p0,
                                          const f32x2 pk0, const f32x2 pk1,
                                          const f32x2 pk2, const f32x2 pk3,
                                          f32x2* __restrict__ Ae, f32x2* __restrict__ Ao) {
    const float bnd = dppmov<0x138>(Ao[3].y);   // wave_shr:1; lane0 reads 0
    f32x2 prev0; prev0.x = bnd; prev0.y = Ao[3].x;
    const f32x2 E0 = Ae[0] + prev0;
    const f32x2 E1 = Ae[1] + Ao[0];
    const f32x2 E2 = Ae[2] + Ao[1];
    const f32x2 E3 = Ae[3] + Ao[2];
    const f32x2 T0 = Ao[0] + E0;
    const f32x2 T1 = Ao[1] + E1;
    const f32x2 T2 = Ao[2] + E2;
    const f32x2 T3 = Ao[3] + E3;
    const f32x2 vp0 = {p0, p0};
    Ae[0] = E0 * vp0; Ae[1] = E1 * vp0; Ae[2] = E2 * vp0; Ae[3] = E3 * vp0;
    Ao[0] = T0 * pk0; Ao[1] = T1 * pk1; Ao[2] = T2 * pk2; Ao[3] = T3 * pk3;
}

// ---------------- Pass B (F32 path): f32 prob ring, zero converts ----------------
__global__ __launch_bounds__(64) void k_ctc_f32(const float* __restrict__ pf32,
                                                const int* __restrict__ text_lens,
                                                const int* __restrict__ mel_lens,
                                                const float* __restrict__ p0arr,
                                                float* __restrict__ losses) {
    const int b    = blockIdx.x;
    const int lane = threadIdx.x;
    const int tl   = text_lens[b];
    const int ml   = mel_lens[b];
    const float4* __restrict__ basef = (const float4*)(pf32 + (size_t)b * T_ * 512); // 128/row
    const float* __restrict__ p0b    = p0arr + (size_t)b * T_;

    // 16-slot ring, 2 float4 per slot; row t lives in slot t&15.
    // Prologue: rows 1..15 -> slots 1..15 (slot 0 is filled at step t=1).
    float4 rawA[16], rawB[16];
#pragma unroll
    for (int s = 1; s < 16; ++s) {
        const float4* __restrict__ rowp = basef + (size_t)s * 128;
        rawA[s] = rowp[2 * lane]; rawB[s] = rowp[2 * lane + 1];
    }
    rawA[0] = rawB[0] = (float4){0.f, 0.f, 0.f, 0.f};

    f32x2 Ae[4], Ao[4];
#pragma unroll
    for (int j = 0; j < 4; ++j) { Ae[j] = (f32x2){0.f, 0.f}; Ao[j] = (f32x2){0.f, 0.f}; }
    {   // alpha0[0] = alpha0[1] = p(t=0, class 0), pre-scaled by 2^66; pair 0 = slot0.x
        const float p00 = p0b[0] * 0x1p66f;
        if (lane == 0) { Ae[0].x = p00; Ao[0].x = p00; }
    }
    int exacc = -66;                  // lognorm = exacc * ln2 at the end
    float p0A = p0b[1], p0B = p0b[2]; // scalar p0 pipeline, 2 steps ahead

    // Step I (t = tb+I, tb == 1 mod 16): consume slot (1+I)&15 directly from ring,
    // reload slot I&15 (consumed last step) with row t+15, refill p0 for t+2.
#define STEPF(I, P0IN, CLAMPED)                                                 \
    {                                                                           \
        constexpr int Sc = (1 + (I)) & 15;                                      \
        constexpr int Sl = (I) & 15;                                            \
        const int t = tb + (I);                                                 \
        f32x2 pk0, pk1, pk2, pk3;                                               \
        pk0.x = rawA[Sc].x; pk0.y = rawA[Sc].y;                                 \
        pk1.x = rawA[Sc].z; pk1.y = rawA[Sc].w;                                 \
        pk2.x = rawB[Sc].x; pk2.y = rawB[Sc].y;                                 \
        pk3.x = rawB[Sc].z; pk3.y = rawB[Sc].w;                                 \
        { int tr = t + 15; if (CLAMPED) { if (tr > ml - 1) tr = ml - 1; }       \
          const float4* __restrict__ rowp = basef + (size_t)tr * 128;           \
          rawA[Sl] = rowp[2 * lane]; rawB[Sl] = rowp[2 * lane + 1]; }           \
        update_pk(P0IN, pk0, pk1, pk2, pk3, Ae, Ao);                            \
        { int t2 = t + 2; if (CLAMPED) { if (t2 > ml - 1) t2 = ml - 1; }        \
          P0IN = p0b[t2]; }                                                     \
        if (((I) & 7) == 7) renorm_exp_pk(Ae, Ao, exacc);                       \
    }

#define BLOCKF(CLAMPED)                                                         \
        STEPF(0,  p0A, CLAMPED)  STEPF(1,  p0B, CLAMPED)                        \
        STEPF(2,  p0A, CLAMPED)  STEPF(3,  p0B, CLAMPED)                        \
        STEPF(4,  p0A, CLAMPED)  STEPF(5,  p0B, CLAMPED)                        \
        STEPF(6,  p0A, CLAMPED)  STEPF(7,  p0B, CLAMPED)                        \
        STEPF(8,  p0A, CLAMPED)  STEPF(9,  p0B, CLAMPED)                        \
        STEPF(10, p0A, CLAMPED)  STEPF(11, p0B, CLAMPED)                        \
        STEPF(12, p0A, CLAMPED)  STEPF(13, p0B, CLAMPED)                        \
        STEPF(14, p0A, CLAMPED)  STEPF(15, p0B, CLAMPED)

    int tb = 1;
    for (; tb + 31 <= ml; tb += 16) {       // steady: loads (t+15 <= tb+30 <= ml-1) never clamp
        BLOCKF(0)
    }
    if (tb + 16 <= ml) {                    // one transition block with clamped loads
        BLOCKF(1)
        tb += 16;
    }

    // tail: rows tb..ml-1 (<16), resident in slots (1+I)&15; no reloads, no renorm
    // (p<=1: shrink-only, <=15 steps of drift stays in fp32 range).
#define STEPF_TAIL(I, P0IN)                                                     \
    if (tb + (I) < ml) {                                                        \
        constexpr int Sc = (1 + (I)) & 15;                                      \
        f32x2 pk0, pk1, pk2, pk3;                                               \
        pk0.x = rawA[Sc].x; pk0.y = rawA[Sc].y;                                 \
        pk1.x = rawA[Sc].z; pk1.y = rawA[Sc].w;                                 \
        pk2.x = rawB[Sc].x; pk2.y = rawB[Sc].y;                                 \
        pk3.x = rawB[Sc].z; pk3.y = rawB[Sc].w;                                 \
        update_pk(P0IN, pk0, pk1, pk2, pk3, Ae, Ao);                            \
        { int t2 = tb + (I) + 2; if (t2 > ml - 1) t2 = ml - 1;                  \
          P0IN = p0b[t2]; }                                                     \
    }
    STEPF_TAIL(0,  p0A)  STEPF_TAIL(1,  p0B)
    STEPF_TAIL(2,  p0A)  STEPF_TAIL(3,  p0B)
    STEPF_TAIL(4,  p0A)  STEPF_TAIL(5,  p0B)
    STEPF_TAIL(6,  p0A)  STEPF_TAIL(7,  p0B)
    STEPF_TAIL(8,  p0A)  STEPF_TAIL(9,  p0B)
    STEPF_TAIL(10, p0A)  STEPF_TAIL(11, p0B)
    STEPF_TAIL(12, p0A)  STEPF_TAIL(13, p0B)
    STEPF_TAIL(14, p0A)  STEPF_TAIL(15, p0B)
#undef STEPF_TAIL
#undef BLOCKF
#undef STEPF

    // epilogue: probs normalized -> ll = ln(contrib) + exacc*ln2
    float contrib = 0.f;
#pragma unroll
    for (int j = 0; j < 4; ++j) {
        const int kx = lane * 8 + j;
        const int ky = kx + 4;
        if (kx == tl)     contrib += Ae[j].x;
        if (kx == tl - 1) contrib += Ao[j].x;
        if (ky == tl)     contrib += Ae[j].y;
        if (ky == tl - 1) contrib += Ao[j].y;
    }
#pragma unroll
    for (int off = 32; off; off >>= 1) contrib += __shfl_xor(contrib, off);
    if (lane == 0) {
        float loss = 0.f;
        if (contrib > 0.f) {
            const float ll = __logf(contrib) + (float)exacc * 0.69314718056f;
            loss = -ll / (float)tl;
        }
        losses[b] = loss;
    }
}

// ---------------- Pass B (BF16 path): R10 kernel verbatim ----------------
__global__ __launch_bounds__(64) void k_ctc_bf16(const unsigned short* __restrict__ pbf,
                                                 const int* __restrict__ text_lens,
                                                 const int* __restrict__ mel_lens,
                                                 const float* __restrict__ p0arr,
                                                 float* __restrict__ losses) {
    const int b    = blockIdx.x;
    const int lane = threadIdx.x;
    const int tl   = text_lens[b];
    const int ml   = mel_lens[b];
    const unsigned short* __restrict__ pb = pbf + (size_t)b * T_ * 512;
    const uint4* __restrict__ base = (const uint4*)pb;       // 64 uint4 per row
    const float* __restrict__ p0b  = p0arr + (size_t)b * T_;

    uint4 raw[16];
#pragma unroll
    for (int s = 0; s < 16; ++s) {
        const uint4* __restrict__ rowp = base + (size_t)(s + 1) * 64;
        raw[s] = rowp[lane];
    }

    f32x2 Ae[4], Ao[4];
#pragma unroll
    for (int j = 0; j < 4; ++j) { Ae[j] = (f32x2){0.f, 0.f}; Ao[j] = (f32x2){0.f, 0.f}; }
    {
        const float p00 = p0b[0] * 0x1p66f;
        if (lane == 0) { Ae[0].x = p00; Ao[0].x = p00; }
    }
    int exacc = -66;

#define CVT8(SLOT, P)  { const uint4 w = raw[SLOT];                                   \
        P[0].x=__uint_as_float(w.x<<16); P[0].y=__uint_as_float(w.x&0xFFFF0000u);     \
        P[1].x=__uint_as_float(w.y<<16); P[1].y=__uint_as_float(w.y&0xFFFF0000u);     \
        P[2].x=__uint_as_float(w.z<<16); P[2].y=__uint_as_float(w.z&0xFFFF0000u);     \
        P[3].x=__uint_as_float(w.w<<16); P[3].y=__uint_as_float(w.w&0xFFFF0000u); }

    f32x2 pA[4], pB[4];
    float p0A = p0b[1], p0B = p0b[2];
    CVT8(0, pA)

#define STEP_MAIN(S, PIN, P0IN, POUT, CLAMPED)                                 \
    { int tr = tb + (S) + 16;                                                  \
      if (CLAMPED) { if (tr > ml - 1) tr = ml - 1; }                           \
      const uint4* __restrict__ rowp = base + (size_t)tr * 64;                 \
      raw[S] = rowp[lane]; }                                                   \
    CVT8(((S) + 1) & 15, POUT)                                                 \
    update_pk(P0IN, PIN[0], PIN[1], PIN[2], PIN[3], Ae, Ao);                   \
    { int t2 = tb + (S) + 2;                                                   \
      if (CLAMPED) { if (t2 > ml - 1) t2 = ml - 1; }                           \
      P0IN = p0b[t2]; }                                                        \
    if (((S) & 7) == 7) renorm_exp_pk(Ae, Ao, exacc);

#define BLOCK16(CLAMPED)                                                       \
        STEP_MAIN(0,  pA, p0A, pB, CLAMPED)                                    \
        STEP_MAIN(1,  pB, p0B, pA, CLAMPED)                                    \
        STEP_MAIN(2,  pA, p0A, pB, CLAMPED)                                    \
        STEP_MAIN(3,  pB, p0B, pA, CLAMPED)                                    \
        STEP_MAIN(4,  pA, p0A, pB, CLAMPED)                                    \
        STEP_MAIN(5,  pB, p0B, pA, CLAMPED)                                    \
        STEP_MAIN(6,  pA, p0A, pB, CLAMPED)                                    \
        STEP_MAIN(7,  pB, p0B, pA, CLAMPED)                                    \
        STEP_MAIN(8,  pA, p0A, pB, CLAMPED)                                    \
        STEP_MAIN(9,  pB, p0B, pA, CLAMPED)                                    \
        STEP_MAIN(10, pA, p0A, pB, CLAMPED)                                    \
        STEP_MAIN(11, pB, p0B, pA, CLAMPED)                                    \
        STEP_MAIN(12, pA, p0A, pB, CLAMPED)                                    \
        STEP_MAIN(13, pB, p0B, pA, CLAMPED)                                    \
        STEP_MAIN(14, pA, p0A, pB, CLAMPED)                                    \
        STEP_MAIN(15, pB, p0B, pA, CLAMPED)

    int tb = 1;
    for (; tb + 32 <= ml; tb += 16) {
        BLOCK16(0)
    }
    if (tb + 16 <= ml) {
        BLOCK16(1)
        tb += 16;
    }

#define STEP_TAIL(S, PIN, P0IN, POUT)                                          \
    if (tb + (S) < ml) {                                                       \
        CVT8(((S) + 1) & 15, POUT)                                             \
        update_pk(P0IN, PIN[0], PIN[1], PIN[2], PIN[3], Ae, Ao);               \
        { int t2 = tb + (S) + 2; if (t2 > ml - 1) t2 = ml - 1;                 \
          P0IN = p0b[t2]; }                                                    \
    }
    STEP_TAIL(0,  pA, p0A, pB)
    STEP_TAIL(1,  pB, p0B, pA)
    STEP_TAIL(2,  pA, p0A, pB)
    STEP_TAIL(3,  pB, p0B, pA)
    STEP_TAIL(4,  pA, p0A, pB)
    STEP_TAIL(5,  pB, p0B, pA)
    STEP_TAIL(6,  pA, p0A, pB)
    STEP_TAIL(7,  pB, p0B, pA)
    STEP_TAIL(8,  pA, p0A, pB)
    STEP_TAIL(9,  pB, p0B, pA)
    STEP_TAIL(10, pA, p0A, pB)
    STEP_TAIL(11, pB, p0B, pA)
    STEP_TAIL(12, pA, p0A, pB)
    STEP_TAIL(13, pB, p0B, pA)
    STEP_TAIL(14, pA, p0A, pB)
    STEP_TAIL(15, pB, p0B, pA)
#undef STEP_TAIL
#undef BLOCK16
#undef STEP_MAIN
#undef CVT8

    float contrib = 0.f;
#pragma unroll
    for (int j = 0; j < 4; ++j) {
        const int kx = lane * 8 + j;
        const int ky = kx + 4;
        if (kx == tl)     contrib += Ae[j].x;
        if (kx == tl - 1) contrib += Ao[j].x;
        if (ky == tl)     contrib += Ae[j].y;
        if (ky == tl - 1) contrib += Ao[j].y;
    }
#pragma unroll
    for (int off = 32; off; off >>= 1) contrib += __shfl_xor(contrib, off);
    if (lane == 0) {
        float loss = 0.f;
        if (contrib > 0.f) {
            const float ll = __logf(contrib) + (float)exacc * 0.69314718056f;
            loss = -ll / (float)tl;
        }
        losses[b] = loss;
    }
}

// ---------------- Pass B (slow fallback, proven R4): direct logit loads ----------------
template <int PP>
__device__ __forceinline__ void step_update(const float p0, const float* __restrict__ p,
                                            float* __restrict__ aeven, float* __restrict__ aodd) {
    float prev = dppmov<0x138>(aodd[PP - 1]);
#pragma unroll
    for (int j = 0; j < PP; ++j) {
        const float oldodd = aodd[j];
        const float e = aeven[j] + prev;
        aeven[j] = e * p0;
        aodd[j]  = (oldodd + e) * p[j];
        prev = oldodd;
    }
}

template <int PP>
__device__ __forceinline__ void renorm(float* __restrict__ aeven, float* __restrict__ aodd,
                                       float& lognorm) {
    float m = 0.f;
#pragma unroll
    for (int j = 0; j < PP; ++j) m = fmaxf(m, fmaxf(aeven[j], aodd[j]));
    m = fmaxf(m, dppmov<0x111>(m));
    m = fmaxf(m, dppmov<0x112>(m));
    m = fmaxf(m, dppmov<0x114>(m));
    m = fmaxf(m, dppmov<0x118>(m));
    m = fmaxf(m, dppmov<0x142>(m));
    m = fmaxf(m, dppmov<0x143>(m));
    const float wm  = __int_as_float(__builtin_amdgcn_readlane(__float_as_int(m), 63));
    const float inv = 1.0f / wm;
    lognorm += __logf(wm) - LOGM0f;
#pragma unroll
    for (int j = 0; j < PP; ++j) {
        aeven[j] = (aeven[j] * inv) * M0f;
        aodd[j]  = (aodd[j]  * inv) * M0f;
    }
}

template <int PP>
__device__ __forceinline__ void ctc_run_slow(const float* __restrict__ Lb, float lsum,
                                             int tl, int ml, float* __restrict__ loss_out) {
    const int lane = threadIdx.x;
    const int base = lane * PP;
    int   idx[PP];
    float mask[PP];
#pragma unroll
    for (int j = 0; j < PP; ++j) {
        const int k = base + j;
        idx[j]  = (k < C_) ? k : (C_ - 1);
        mask[j] = (k < tl) ? 1.f : 0.f;
    }
    float raw[8][PP];
#pragma unroll
    for (int s = 0; s < 8; ++s) {
        const float* __restrict__ rowp = Lb + (size_t)(s + 1) * C_;
#pragma unroll
        for (int j = 0; j < PP; ++j) raw[s][j] = rowp[idx[j]];
    }
    float aeven[PP], aodd[PP];
#pragma unroll
    for (int j = 0; j < PP; ++j) { aeven[j] = 0.f; aodd[j] = 0.f; }
    {
        const float a00 = __expf(Lb[0]) * M0f;
        if (lane == 0) { aeven[0] = a00; aodd[0] = a00; }
    }
    float lognorm = -LOGM0f;
    int tb = 1;
    for (; tb + 8 <= ml; tb += 8) {
#pragma unroll
        for (int s = 0; s < 8; ++s) {
            const int tt = tb + s;
            const float p0 = __expf(bcast0(raw[s][0]));
            float p[PP];
#pragma unroll
            for (int j = 0; j < PP; ++j) p[j] = __expf(raw[s][j]) * mask[j];
            { int tr = tt + 8; if (tr > ml - 1) tr = ml - 1;
              const float* __restrict__ rowp = Lb + (size_t)tr * C_;
#pragma unroll
              for (int j = 0; j < PP; ++j) raw[s][j] = rowp[idx[j]]; }
            step_update<PP>(p0, p, aeven, aodd);
            if (s == 7) renorm<PP>(aeven, aodd, lognorm);
        }
    }
#pragma unroll
    for (int s = 0; s < 8; ++s) {
        const int tt = tb + s;
        if (tt < ml) {
            const float p0 = __expf(bcast0(raw[s][0]));
            float p[PP];
#pragma unroll
            for (int j = 0; j < PP; ++j) p[j] = __expf(raw[s][j]) * mask[j];
            step_update<PP>(p0, p, aeven, aodd);
            if (s == 7) renorm<PP>(aeven, aodd, lognorm);
        }
    }
    float contrib = 0.f;
#pragma unroll
    for (int j = 0; j < PP; ++j) {
        const int k = base + j;
        if (k == tl)     contrib += aeven[j];
        if (k == tl - 1) contrib += aodd[j];
    }
#pragma unroll
    for (int off = 32; off; off >>= 1) contrib += __shfl_xor(contrib, off);
    if (lane == 0) {
        float loss = 0.f;
        if (contrib > 0.f) {
            const float ll = __logf(contrib) + lognorm - lsum;   // raw domain: -lsum needed
            loss = -ll / (float)tl;
        }
        *loss_out = loss;
    }
}

__global__ __launch_bounds__(64) void k_ctc_slow(const float* __restrict__ logits,
                                                 const int* __restrict__ text_lens,
                                                 const int* __restrict__ mel_lens,
                                                 const float* __restrict__ lsums,
                                                 float* __restrict__ losses) {
    const int b  = blockIdx.x;
    const int tl = text_lens[b];
    const int ml = mel_lens[b];
    const float lsum = lsums[b];
    const float* Lb = logits + (size_t)b * T_ * C_;
    float* lo = losses + b;
    const int PP = (tl + 1 + 63) >> 6;
    switch (PP) {
        case 1: ctc_run_slow<1>(Lb, lsum, tl, ml, lo); break;
        case 2: ctc_run_slow<2>(Lb, lsum, tl, ml, lo); break;
        case 3: ctc_run_slow<3>(Lb, lsum, tl, ml, lo); break;
        case 4: ctc_run_slow<4>(Lb, lsum, tl, ml, lo); break;
        case 5: ctc_run_slow<5>(Lb, lsum, tl, ml, lo); break;
        case 6: ctc_run_slow<6>(Lb, lsum, tl, ml, lo); break;
        default: ctc_run_slow<7>(Lb, lsum, tl, ml, lo); break;
    }
}

// ---------------- Pass C: deterministic mean ----------------
__global__ __launch_bounds__(64) void k_final(const float* __restrict__ losses,
                                              float* __restrict__ out) {
    const int lane = threadIdx.x;
    float v = (lane < B_) ? losses[lane] : 0.f;
#pragma unroll
    for (int off = 32; off; off >>= 1) v += __shfl_xor(v, off);
    if (lane == 0) out[0] = v * (1.0f / B_);
}

extern "C" void kernel_launch(void* const* d_in, const int* in_sizes, int n_in,
                              void* d_out, int out_size, void* d_ws, size_t ws_size,
                              hipStream_t stream) {
    const float* logits    = (const float*)d_in[0];   // [B,1,T,C] fp32
    const int*   text_lens = (const int*)d_in[1];     // [B] int32
    const int*   mel_lens  = (const int*)d_in[2];     // [B] int32
    float* out = (float*)d_out;

    const size_t PF32_BYTES = (size_t)B_ * T_ * 512 * 4;          // 131,072,000
    const size_t PBF_BYTES  = (size_t)B_ * T_ * 512 * 2;          //  65,536,000
    const size_t tail_bytes = (size_t)B_ * T_ * 4 + 2 * B_ * 4 + 64;

    if (ws_size >= PF32_BYTES + tail_bytes) {
        float* pf32   = (float*)d_ws;
        float* ls     = (float*)((char*)d_ws + PF32_BYTES);   // p0[t]
        float* lsums  = ls + (size_t)B_ * T_;
        float* losses = lsums + B_;
        k_prob<<<B_ * T_ / 4, 256, 0, stream>>>(logits, text_lens, pf32, nullptr, ls);
        k_ctc_f32<<<B_, 64, 0, stream>>>(pf32, text_lens, mel_lens, ls, losses);
        k_final<<<1, 64, 0, stream>>>(losses, out);
    } else if (ws_size >= PBF_BYTES + tail_bytes) {
        unsigned short* pbf = (unsigned short*)d_ws;
        float* ls     = (float*)((char*)d_ws + PBF_BYTES);    // p0[t]
        float* lsums  = ls + (size_t)B_ * T_;
        float* losses = lsums + B_;
        k_prob<<<B_ * T_ / 4, 256, 0, stream>>>(logits, text_lens, nullptr, pbf, ls);
        k_ctc_bf16<<<B_, 64, 0, stream>>>(pbf, text_lens, mel_lens, ls, losses);
        k_final<<<1, 64, 0, stream>>>(losses, out);
    } else {
        float* ls     = (float*)d_ws;
        float* lsums  = ls + (size_t)B_ * T_;
        float* losses = lsums + B_;
        k_prob<<<B_ * T_ / 4, 256, 0, stream>>>(logits, text_lens, nullptr, nullptr, ls);
        k_lsum<<<B_, 256, 0, stream>>>(ls, mel_lens, lsums);
        k_ctc_slow<<<B_, 64, 0, stream>>>(logits, text_lens, mel_lens, lsums, losses);
        k_final<<<1, 64, 0, stream>>>(losses, out);
    }
}